// Round 7
// baseline (365.154 us; speedup 1.0000x reference)
//
#include <hip/hip_runtime.h>
#include <hip/hip_fp16.h>
#include <cstdint>
#include <cstddef>

#define Nn 50000
#define Ne 800000
#define Ng 1024
#define NFd 32
#define Rr 4
#define Hd 64
#define Od 16
#define MAXD 10
#define NSEG (Nn * Rr)
#define SCAN_BLK ((NSEG + 255) / 256)
#define ORDER_SZ (Nn + 176)                // buckets padded to x16 (11*15=165 max pad); /16 exact
#define NB_MF (ORDER_SZ / 16)              // block = 16 slots (degree-uniform), 4 waves
#define NB_RG (Nn / 16)                    // block = 4 waves; 16 nodes/block (MFMA tile)
#define NB_RELSEG (Ne / 256)               // 3125 edge blocks
#define NB_EMBED (Nn / 8)                  // 6250 embed blocks (2 nodes/wave)
#define WT_PER_LAYER (Hd * 5 * Hd)         // 20480 halves: [64 cols][320 k]
#define MFWT_PER_LAYER ((MAXD + 1) * Hd * 2 * Hd)  // 90112 halves: [d][64 cols][128 k]
#define PREP_TOTAL (2 * WT_PER_LAYER + 2 * MFWT_PER_LAYER)

typedef _Float16 f16x8 __attribute__((ext_vector_type(8)));
typedef float f32x4 __attribute__((ext_vector_type(4)));

__device__ __forceinline__ float reluf(float v) { return v > 0.f ? v : 0.f; }
__device__ __forceinline__ int rfl(int v) { return __builtin_amdgcn_readfirstlane(v); }

// ---- FUSED: per-edge relation argmax + no-return seg count + embedding lookup ----
// rank[] is gone: scatter derives positions via fill[] atomics. Embed: 2 nodes/wave.
__global__ void k_rel_emb(const float4* __restrict__ ea, const int* __restrict__ eidx,
                          int* __restrict__ seg, int* __restrict__ cnt,
                          const float* __restrict__ x, const float* __restrict__ emb,
                          __half* __restrict__ h16) {
    if (blockIdx.x < NB_RELSEG) {
        int e = blockIdx.x * 256 + threadIdx.x;     // grid sized exactly: e < Ne
        float4 a = ea[e];
        int bi = 0; float bv = a.x;
        if (a.y > bv) { bv = a.y; bi = 1; }
        if (a.z > bv) { bv = a.z; bi = 2; }
        if (a.w > bv) { bv = a.w; bi = 3; }
        int s = eidx[Ne + e] * Rr + bi;
        seg[e] = s;
        atomicAdd(&cnt[s], 1);                      // no return -> fire-and-forget
    } else {
        int wave = ((blockIdx.x - NB_RELSEG) * 256 + threadIdx.x) >> 6;  // < Nn/2
        int lane = threadIdx.x & 63;
        int h = lane >> 5, q = lane & 31;
        int node = wave * 2 + h;
        float v = x[(size_t)node * NFd + q];
        int idx = q;
        #pragma unroll
        for (int o = 16; o >= 1; o >>= 1) {         // xor-butterfly within half-wave
            float ov = __shfl_xor(v, o);
            int oi = __shfl_xor(idx, o);
            if (ov > v || (ov == v && oi < idx)) { v = ov; idx = oi; }
        }
        const float2* e2 = (const float2*)(emb + (size_t)idx * Hd);
        float2 ev = e2[q];
        ((__half2*)h16)[(size_t)node * 32 + q] =
            __floats2half2_rn(reluf(ev.x), reluf(ev.y));
    }
}

// ---- prep: fp16 transposed-stacked weights for both MFMA transforms ----
__global__ void k_prep(const float* __restrict__ w0, const float* __restrict__ r0,
                       const float* __restrict__ w1, const float* __restrict__ r1,
                       const float* __restrict__ wl0, const float* __restrict__ wr0,
                       const float* __restrict__ wl1, const float* __restrict__ wr1,
                       __half* __restrict__ wt, __half* __restrict__ mfwt) {
    int idx = blockIdx.x * 256 + threadIdx.x;
    if (idx < 2 * WT_PER_LAYER) {
        int b = idx / WT_PER_LAYER;
        int rem = idx % WT_PER_LAYER;
        int c = rem / 320;
        int k = rem % 320;
        const float* W  = b ? w1 : w0;
        const float* Rt = b ? r1 : r0;
        float v = (k < 64) ? Rt[k * Hd + c]
                           : W[((size_t)((k - 64) >> 6)) * Hd * Hd + ((k - 64) & 63) * Hd + c];
        wt[idx] = __float2half(v);
    } else if (idx < PREP_TOTAL) {
        int j = idx - 2 * WT_PER_LAYER;
        int b = j / MFWT_PER_LAYER;
        int rem = j % MFWT_PER_LAYER;
        int d = rem / (Hd * 128);
        int r2 = rem % (Hd * 128);
        int c = r2 / 128;
        int k = r2 % 128;
        const float* Wl = b ? wl1 : wl0;
        const float* Wr = b ? wr1 : wr0;
        float v = (k < 64) ? Wl[(size_t)d * Hd * Hd + k * Hd + c]
                           : Wr[(size_t)d * Hd * Hd + (k - 64) * Hd + c];
        mfwt[j] = __float2half(v);
    }
}

// ---- scan level 1 + fused degree histogram ----
__global__ void k_scan1(const int* __restrict__ cnt, int* __restrict__ off,
                        int* __restrict__ bsum, int* __restrict__ bcnt) {
    __shared__ int s[256];
    __shared__ int hist[16];
    int t = threadIdx.x;
    if (t < 16) hist[t] = 0;
    int idx = blockIdx.x * 256 + t;
    int v = (idx < NSEG) ? cnt[idx] : 0;
    s[t] = v;
    __syncthreads();
    if ((t & 3) == 0 && idx < NSEG) {
        int dsum = s[t] + s[t + 1] + s[t + 2] + s[t + 3];
        atomicAdd(&hist[min(dsum, MAXD)], 1);
    }
    #pragma unroll
    for (int o = 1; o < 256; o <<= 1) {
        int x = (t >= o) ? s[t - o] : 0;
        __syncthreads();
        s[t] += x;
        __syncthreads();
    }
    if (idx < NSEG) off[idx] = s[t] - v;            // exclusive
    if (t == 255) bsum[blockIdx.x] = s[255];
    if (t < 16) {
        int h = hist[t];
        if (h > 0) atomicAdd(&bcnt[t], h);
    }
}

// ---- scan level 2 + fused bucket prefix (16-aligned) + order pad-slot writes ----
__global__ void k_scan2(int* __restrict__ bsum, const int* __restrict__ bcnt,
                        int* __restrict__ bbase, int* __restrict__ order) {
    __shared__ int s[1024];
    int t = threadIdx.x;
    int v = (t < SCAN_BLK) ? bsum[t] : 0;
    s[t] = v;
    __syncthreads();
    #pragma unroll
    for (int o = 1; o < 1024; o <<= 1) {
        int x = (t >= o) ? s[t - o] : 0;
        __syncthreads();
        s[t] += x;
        __syncthreads();
    }
    if (t < SCAN_BLK) bsum[t] = s[t] - v;           // exclusive block bases
    if (t == 0) {
        int run = 0;
        for (int d = 0; d <= MAXD; d++) {
            int c = bcnt[d];
            bbase[d] = run;
            int pad = (c + 15) & ~15;               // x16: MFMA tile = degree-uniform
            for (int i = c; i < pad; i++) order[run + i] = -1;
            run += pad;
        }
        for (int i = run; i < ORDER_SZ; i++) order[i] = -1;
    }
}

// ---- FUSED: scan level 3 (final off + fill copy)  +  degree-bucket scatter ----
__global__ void k_scan3_bucket(int* __restrict__ off, const int* __restrict__ bsum,
                               const int4* __restrict__ cnt4, const int* __restrict__ bbase,
                               int* __restrict__ bfill, int* __restrict__ order,
                               int* __restrict__ fill) {
    __shared__ int hist[16];
    __shared__ int base[16];
    int t = threadIdx.x;
    if (t < 16) hist[t] = 0;
    __syncthreads();
    int idx = blockIdx.x * 256 + t;
    if (idx == 0) off[NSEG] = Ne;
    if (idx < NSEG) {
        int v = off[idx] + bsum[blockIdx.x];
        off[idx] = v;
        fill[idx] = v;                              // scatter's atomic fill pointers
    }
    int d = 0, rk = 0;
    bool valid = (idx < Nn);
    if (valid) {
        int4 c = cnt4[idx];
        d = min(c.x + c.y + c.z + c.w, MAXD);
        rk = atomicAdd(&hist[d], 1);
    }
    __syncthreads();
    if (t < 16) {
        int h = hist[t];
        base[t] = (h > 0) ? atomicAdd(&bfill[t], h) : 0;
    }
    __syncthreads();
    if (valid) order[bbase[d] + base[d] + rk] = idx | (d << 20);
}

// ---- scatter edges into segment-sorted order via fill atomics ----
__global__ void k_scatter(const int* __restrict__ eidx, const int* __restrict__ seg,
                          int* __restrict__ fill, int* __restrict__ sorted_src) {
    int e = blockIdx.x * 256 + threadIdx.x;
    if (e >= Ne) return;
    int pos = atomicAdd(&fill[seg[e]], 1);
    sorted_src[pos] = eidx[e];
}

// ---- FUSED RGCN layer: paired-edge fp16 gather (4B/lane) -> MFMA transform ----
// Half-wave h processes edge t+h of each pair; lane q=lane&31 holds cols {2q,2q+1}.
// Segment sums via per-half prefix snapshots; odd (mid-pair) boundaries subtract
// half1's just-added value (exact). Emits are wave-uniform scalar branches.
__global__ __launch_bounds__(256) void k_rgcn_fused(
        const __half* __restrict__ hin16,
        const int* __restrict__ off, const int* __restrict__ ssrc,
        const __half* __restrict__ wt, const float* __restrict__ bias,
        __half* __restrict__ hout16) {
    __shared__ __align__(16) __half alds[16 * 296];  // [node]: rel*72 + k; node stride 296
    int tid = threadIdx.x;
    int wv = tid >> 6, lane = tid & 63;
    int h = lane >> 5, q = lane & 31;
    int nblk = rfl(blockIdx.x * 16);
    int n0 = nblk + wv * 4;
    int obv = off[4 * n0 + min(lane, 16)];          // boundaries live in lanes
    int cntv = __shfl(obv, lane + 1) - obv;
    float ivv = (cntv > 0) ? 1.f / (float)cntv : 0.f;
    int e    = rfl(__shfl(obv, 0));
    int eEnd = rfl(__shfl(obv, 16));
    const __half2* hp = (const __half2*)hin16;      // row = 32 half2

    float ax = 0.f, ay = 0.f;                       // running prefix (per half)
    float px = 0.f, py = 0.f;                       // snapshot
    float vx = 0.f, vy = 0.f;                       // half's most recent added value
    int segi = 0;
    int nb = rfl(__shfl(obv, 1));

#define EMIT(SUB) do {                                               \
        float dx = ax - px, dy = ay - py;                            \
        float ox = ((SUB) && h) ? vx : 0.f;                          \
        float oy = ((SUB) && h) ? vy : 0.f;                          \
        dx -= ox; dy -= oy;                                          \
        dx += __shfl_xor(dx, 32); dy += __shfl_xor(dy, 32);          \
        float iv_ = __shfl(ivv, segi);                               \
        if (lane < 32)                                               \
            *(__half2*)&alds[(wv * 4 + (segi >> 2)) * 296            \
                             + (segi & 3) * 72 + 2 * q]              \
                = __floats2half2_rn(dx * iv_, dy * iv_);             \
        px = ax - ox; py = ay - oy;                                  \
        segi++;                                                      \
        nb = (segi < 16) ? rfl(__shfl(obv, segi + 1)) : 0x7fffffff;  \
    } while (0)

#define PSTEP(dj, t0) {                                              \
        while ((t0) == nb) EMIT(0);                                  \
        float2 f_ = __half22float2(dj);                              \
        vx = f_.x; vy = f_.y; ax += f_.x; ay += f_.y;                \
        while ((t0) + 1 == nb) EMIT(1); }

    if (e + 16 <= eEnd) {
        int4 iA = *(const int4*)(ssrc + e);
        int4 iB = *(const int4*)(ssrc + e + 4);
        int4 iC = *(const int4*)(ssrc + e + 8);
        int4 iD = *(const int4*)(ssrc + e + 12);
        while (true) {
            int s0 = h ? iA.y : iA.x;               // pair j: edges e+2j, e+2j+1
            int s1 = h ? iA.w : iA.z;
            int s2 = h ? iB.y : iB.x;
            int s3 = h ? iB.w : iB.z;
            int s4 = h ? iC.y : iC.x;
            int s5 = h ? iC.w : iC.z;
            int s6 = h ? iD.y : iD.x;
            int s7 = h ? iD.w : iD.z;
            __half2 d0 = hp[s0 * 32 + q];           // 8 paired loads in flight
            __half2 d1 = hp[s1 * 32 + q];
            __half2 d2 = hp[s2 * 32 + q];
            __half2 d3 = hp[s3 * 32 + q];
            __half2 d4 = hp[s4 * 32 + q];
            __half2 d5 = hp[s5 * 32 + q];
            __half2 d6 = hp[s6 * 32 + q];
            __half2 d7 = hp[s7 * 32 + q];
            int en = e + 16;
            bool more = (en + 16 <= eEnd);
            int4 jA, jB, jC, jD;
            if (more) {                             // prefetch next chunk's indices
                jA = *(const int4*)(ssrc + en);
                jB = *(const int4*)(ssrc + en + 4);
                jC = *(const int4*)(ssrc + en + 8);
                jD = *(const int4*)(ssrc + en + 12);
            }
            PSTEP(d0, e + 0)  PSTEP(d1, e + 2)  PSTEP(d2, e + 4)  PSTEP(d3, e + 6)
            PSTEP(d4, e + 8)  PSTEP(d5, e + 10) PSTEP(d6, e + 12) PSTEP(d7, e + 14)
            e = en;
            if (!more) break;
            iA = jA; iB = jB; iC = jC; iD = jD;
        }
    }
    for (; e + 2 <= eEnd; e += 2) {                 // tail pairs
        while (e == nb) EMIT(0);
        int sa = rfl(ssrc[e]), sb = rfl(ssrc[e + 1]);
        int s = h ? sb : sa;
        float2 f = __half22float2(hp[s * 32 + q]);
        vx = f.x; vy = f.y; ax += f.x; ay += f.y;
        while (e + 1 == nb) EMIT(1);
    }
    if (e < eEnd) {                                 // final single edge (half0 only)
        while (e == nb) EMIT(0);
        int sa = rfl(ssrc[e]);
        float2 f = __half22float2(hp[sa * 32 + q]);
        if (h) { f.x = 0.f; f.y = 0.f; }
        ax += f.x; ay += f.y;
        e++;
    }
    while (segi < 16) EMIT(0);                      // drain (no subtraction needed)
#undef PSTEP
#undef EMIT

    __syncthreads();                                // waves share the A tile now

    // ---- MFMA transform: wave wv -> output cols [16wv, 16wv+16), 16 nodes ----
    int rp = lane & 15;
    int g  = lane >> 4;
    const __half* ha = hin16 + (size_t)(nblk + rp) * Hd + 8 * g;
    const __half* ba = wt + (size_t)(wv * 16 + rp) * 320 + 8 * g;
    const __half* aa = alds + rp * 296 + 8 * g;
    f32x4 dacc = {0.f, 0.f, 0.f, 0.f};
    #pragma unroll
    for (int s = 0; s < 10; s++) {                  // k0 = 32*s; a-source matches (32s)
        f16x8 bfrag = *(const f16x8*)(ba + s * 32);
        f16x8 afrag;
        if (s < 2) afrag = *(const f16x8*)(ha + s * 32);
        else       afrag = *(const f16x8*)(aa + ((s - 2) >> 1) * 72 + ((s - 2) & 1) * 32);
        dacc = __builtin_amdgcn_mfma_f32_16x16x32_f16(afrag, bfrag, dacc, 0, 0, 0);
    }
    int c = wv * 16 + rp;
    float bb = bias[c];
    #pragma unroll
    for (int j = 0; j < 4; j++) {
        int row = nblk + g * 4 + j;
        float v = reluf(dacc[j] + bb);
        hout16[(size_t)row * Hd + c] = __float2half(v);   // fp32 out dropped (dead)
    }
}

// ---- FUSED MFConv layer: 4-group fp16 gather (8B/lane) -> LDS -> MFMA ----
// Lane group g2=lane>>4 processes edge 4j+g2; lane q4=lane&15 holds cols 4q4..4q4+3.
__global__ __launch_bounds__(256) void k_mf_fused(
        const __half* __restrict__ hin16,
        const int* __restrict__ off, const int* __restrict__ ssrc,
        const int* __restrict__ order, const __half* __restrict__ mfwt,
        const float* __restrict__ bl,
        float* __restrict__ hout, __half* __restrict__ hout16, int relu_out) {
    __shared__ __align__(16) __half alds[16 * 72];  // 2.25 KB: [slot][k], stride 72
    int tid = threadIdx.x;
    int wv = tid >> 6, lane = tid & 63;
    int g2 = lane >> 4, q4 = lane & 15;
    int blk = rfl(blockIdx.x * 16);
    int ent0 = rfl(order[blk]);
    if (ent0 < 0) return;                           // entire block is pad
    int d = ent0 >> 20;
    const uint2* hp2 = (const uint2*)hin16;         // row = 16 uint2 (8B = 4 halves)

#define SEL4(v4) ((g2 & 2) ? ((g2 & 1) ? (v4).w : (v4).z) : ((g2 & 1) ? (v4).y : (v4).x))
#define ACC8(dw) { float2 f_ = __half22float2(*(__half2*)&(dw).x);   \
                   float2 g_ = __half22float2(*(__half2*)&(dw).y);   \
                   a0 += f_.x; a1 += f_.y; a2 += g_.x; a3 += g_.y; }

    for (int i = 0; i < 4; i++) {                   // wave gathers its 4 slots
        int slot = blk + wv * 4 + i;
        int ent = rfl(order[slot]);
        float a0 = 0.f, a1 = 0.f, a2 = 0.f, a3 = 0.f;
        if (ent >= 0) {
            int n = ent & 0xFFFFF;
            int e0 = rfl(off[n * Rr]);
            int e4 = rfl(off[n * Rr + Rr]);
            int e = e0;
            for (; e + 16 <= e4; e += 16) {         // 16 edges = 4 quad-instructions
                int4 iA = *(const int4*)(ssrc + e);
                int4 iB = *(const int4*)(ssrc + e + 4);
                int4 iC = *(const int4*)(ssrc + e + 8);
                int4 iD = *(const int4*)(ssrc + e + 12);
                int sA = SEL4(iA), sB = SEL4(iB), sC = SEL4(iC), sD = SEL4(iD);
                uint2 dA = hp2[(size_t)sA * 16 + q4];
                uint2 dB = hp2[(size_t)sB * 16 + q4];
                uint2 dC = hp2[(size_t)sC * 16 + q4];
                uint2 dD = hp2[(size_t)sD * 16 + q4];
                ACC8(dA) ACC8(dB) ACC8(dC) ACC8(dD)
            }
            for (; e + 4 <= e4; e += 4) {
                int4 iA = *(const int4*)(ssrc + e);
                int sA = SEL4(iA);
                uint2 dA = hp2[(size_t)sA * 16 + q4];
                ACC8(dA)
            }
            int rem = e4 - e;
            if (rem > 0) {                          // masked final quad (per-lane s)
                int idxe = e + g2;
                int sl = ssrc[(idxe < e4) ? idxe : (e4 - 1)];
                uint2 dA = hp2[(size_t)sl * 16 + q4];
                float2 f = __half22float2(*(__half2*)&dA.x);
                float2 g = __half22float2(*(__half2*)&dA.y);
                if (idxe >= e4) { f.x = 0.f; f.y = 0.f; g.x = 0.f; g.y = 0.f; }
                a0 += f.x; a1 += f.y; a2 += g.x; a3 += g.y;
            }
        }
        a0 += __shfl_xor(a0, 16); a0 += __shfl_xor(a0, 32);   // combine 4 groups
        a1 += __shfl_xor(a1, 16); a1 += __shfl_xor(a1, 32);
        a2 += __shfl_xor(a2, 16); a2 += __shfl_xor(a2, 32);
        a3 += __shfl_xor(a3, 16); a3 += __shfl_xor(a3, 32);
        if (lane < 16) {
            __half2* dst = (__half2*)&alds[(wv * 4 + i) * 72 + 4 * q4];
            dst[0] = __floats2half2_rn(a0, a1);
            dst[1] = __floats2half2_rn(a2, a3);
        }
    }
#undef SEL4
#undef ACC8
    __syncthreads();

    // ---- MFMA: wave wv -> output cols [16wv,16wv+16), rows = 16 tile slots ----
    int rp = lane & 15;
    int g  = lane >> 4;
    int entr = order[blk + rp];                     // per-lane row entry (L2-hot)
    int nr = (entr >= 0) ? (entr & 0xFFFFF) : 0;
    const __half* aa = alds + rp * 72 + 8 * g;
    const __half* ha = hin16 + (size_t)nr * Hd + 8 * g;
    const __half* ba = mfwt + ((size_t)d * Hd + wv * 16 + rp) * 128 + 8 * g;
    f32x4 dacc = {0.f, 0.f, 0.f, 0.f};
    #pragma unroll
    for (int s = 0; s < 4; s++) {                   // K=128: k<64 agg@Wl, k>=64 h@Wr
        f16x8 bfrag = *(const f16x8*)(ba + s * 32);
        f16x8 afrag = (s < 2) ? *(const f16x8*)(aa + s * 32)
                              : *(const f16x8*)(ha + (s - 2) * 32);
        dacc = __builtin_amdgcn_mfma_f32_16x16x32_f16(afrag, bfrag, dacc, 0, 0, 0);
    }
    int c = wv * 16 + rp;
    float bb = bl[d * Hd + c];
    #pragma unroll
    for (int j = 0; j < 4; j++) {
        int entw = order[blk + g * 4 + j];
        if (entw >= 0) {
            int n = entw & 0xFFFFF;
            float v = dacc[j] + bb;
            if (relu_out) hout16[(size_t)n * Hd + c] = __float2half(reluf(v));
            else          hout[(size_t)n * Hd + c] = v;   // pool path (layer 1)
        }
    }
}

// ---- global add pool (batch_idx is sorted -> mostly single fused atomic) ----
__global__ void k_pool(const float* __restrict__ h, const int* __restrict__ batch,
                       float* __restrict__ g) {
    int wave = rfl((blockIdx.x * 256 + threadIdx.x) >> 6);
    int lane = threadIdx.x & 63;
    int n0 = wave * 4;
    if (n0 >= Nn) return;
    int b0 = batch[n0], b1 = batch[n0 + 1], b2 = batch[n0 + 2], b3 = batch[n0 + 3];
    float v0 = h[(size_t)n0 * Hd + lane];
    float v1 = h[(size_t)(n0 + 1) * Hd + lane];
    float v2 = h[(size_t)(n0 + 2) * Hd + lane];
    float v3 = h[(size_t)(n0 + 3) * Hd + lane];
    if (b0 == b1 && b0 == b2 && b0 == b3) {
        unsafeAtomicAdd(&g[(size_t)b0 * Hd + lane], v0 + v1 + v2 + v3);
    } else {
        unsafeAtomicAdd(&g[(size_t)b0 * Hd + lane], v0);
        unsafeAtomicAdd(&g[(size_t)b1 * Hd + lane], v1);
        unsafeAtomicAdd(&g[(size_t)b2 * Hd + lane], v2);
        unsafeAtomicAdd(&g[(size_t)b3 * Hd + lane], v3);
    }
}

// ---- head: relu(g@lin1+b1)@lin2+b2, one wave per graph ----
__global__ void k_head(const float* __restrict__ g, const float* __restrict__ w1,
                       const float* __restrict__ b1, const float* __restrict__ w2,
                       const float* __restrict__ b2, float* __restrict__ out) {
    __shared__ float t[4][Hd];
    int wv = threadIdx.x >> 6;
    int lane = threadIdx.x & 63;
    int gi = blockIdx.x * 4 + wv;
    float acc = b1[lane];
    for (int k = 0; k < Hd; k++) acc += g[(size_t)gi * Hd + k] * w1[k * Hd + lane];
    t[wv][lane] = reluf(acc);
    __syncthreads();
    if (lane < Od) {
        float o = b2[lane];
        for (int k = 0; k < Hd; k++) o += t[wv][k] * w2[k * Od + lane];
        out[(size_t)gi * Od + lane] = o;
    }
}

extern "C" void kernel_launch(void* const* d_in, const int* in_sizes, int n_in,
                              void* d_out, int out_size, void* d_ws, size_t ws_size,
                              hipStream_t stream) {
    const float* x      = (const float*)d_in[0];
    const float* ea     = (const float*)d_in[1];
    const int*   eidx   = (const int*)d_in[2];
    const int*   batch  = (const int*)d_in[3];
    const float* emb    = (const float*)d_in[4];
    const float* lin1_w = (const float*)d_in[5];
    const float* lin1_b = (const float*)d_in[6];
    const float* lin2_w = (const float*)d_in[7];
    const float* lin2_b = (const float*)d_in[8];
    const float* rgcn_w[2]    = {(const float*)d_in[9],  (const float*)d_in[15]};
    const float* rgcn_root[2] = {(const float*)d_in[10], (const float*)d_in[16]};
    const float* rgcn_b[2]    = {(const float*)d_in[11], (const float*)d_in[17]};
    const float* mf_wl[2]     = {(const float*)d_in[12], (const float*)d_in[18]};
    const float* mf_bl[2]     = {(const float*)d_in[13], (const float*)d_in[19]};
    const float* mf_wr[2]     = {(const float*)d_in[14], (const float*)d_in[20]};

    char* p = (char*)d_ws;
    float* h32   = (float*)p; p += sizeof(float) * (size_t)Nn * Hd;
    __half* h16a = (__half*)p; p += sizeof(__half) * (size_t)Nn * Hd;
    __half* h16b = (__half*)p; p += sizeof(__half) * (size_t)Nn * Hd;
    float* gbuf  = (float*)p; p += sizeof(float) * (size_t)Ng * Hd;
    __half* wt16 = (__half*)p; p += sizeof(__half) * (size_t)2 * WT_PER_LAYER;
    __half* mfwt16 = (__half*)p; p += sizeof(__half) * (size_t)2 * MFWT_PER_LAYER;
    int* seg     = (int*)p;   p += sizeof(int) * (size_t)Ne;
    int* ssrc    = (int*)p;   p += sizeof(int) * (size_t)Ne;
    int* fill    = (int*)p;   p += sizeof(int) * (size_t)NSEG;
    int* cnt     = (int*)p;   p += sizeof(int) * (size_t)NSEG;  // contiguous with bcnt/bfill
    int* bcnt    = (int*)p;   p += sizeof(int) * 16;
    int* bfill   = (int*)p;   p += sizeof(int) * 16;
    int* off     = (int*)p;   p += sizeof(int) * (size_t)(NSEG + 1);
    int* bsum    = (int*)p;   p += sizeof(int) * 1024;
    int* bbase   = (int*)p;   p += sizeof(int) * 16;
    int* order   = (int*)p;   p += sizeof(int) * (size_t)ORDER_SZ;

    hipMemsetAsync(cnt, 0, sizeof(int) * ((size_t)NSEG + 32), stream);
    hipMemsetAsync(gbuf, 0, sizeof(float) * (size_t)Ng * Hd, stream);

    k_prep<<<(PREP_TOTAL + 255) / 256, 256, 0, stream>>>(
        rgcn_w[0], rgcn_root[0], rgcn_w[1], rgcn_root[1],
        mf_wl[0], mf_wr[0], mf_wl[1], mf_wr[1], wt16, mfwt16);
    k_rel_emb<<<NB_RELSEG + NB_EMBED, 256, 0, stream>>>((const float4*)ea, eidx, seg,
                                                        cnt, x, emb, h16a);
    k_scan1<<<SCAN_BLK, 256, 0, stream>>>(cnt, off, bsum, bcnt);
    k_scan2<<<1, 1024, 0, stream>>>(bsum, bcnt, bbase, order);
    k_scan3_bucket<<<SCAN_BLK, 256, 0, stream>>>(off, bsum, (const int4*)cnt, bbase,
                                                 bfill, order, fill);
    k_scatter<<<Ne / 256, 256, 0, stream>>>(eidx, seg, fill, ssrc);

    __half* hin16 = h16a;  __half* hout16 = h16b;
    for (int b = 0; b < 2; b++) {
        k_rgcn_fused<<<NB_RG, 256, 0, stream>>>(hin16, off, ssrc, wt16 + b * WT_PER_LAYER,
                                                rgcn_b[b], hout16);
        k_mf_fused<<<NB_MF, 256, 0, stream>>>(hout16, off, ssrc, order,
                                              mfwt16 + b * MFWT_PER_LAYER, mf_bl[b],
                                              h32, hin16, b == 0 ? 1 : 0);
        // b=0: mf writes fp16 shadow into hin16 (next layer); b=1: fp32 into h32 (pool)
    }
    k_pool<<<Nn / 16, 256, 0, stream>>>(h32, batch, gbuf);
    k_head<<<Ng / 4, 256, 0, stream>>>(gbuf, lin1_w, lin1_b, lin2_w, lin2_b, (float*)d_out);
}

// Round 8
// 342.605 us; speedup vs baseline: 1.0658x; 1.0658x over previous
//
#include <hip/hip_runtime.h>
#include <hip/hip_fp16.h>
#include <cstdint>
#include <cstddef>

#define Nn 50000
#define Ne 800000
#define Ng 1024
#define NFd 32
#define Rr 4
#define Hd 64
#define Od 16
#define MAXD 10
#define NSEG (Nn * Rr)
#define SCAN_BLK ((NSEG + 255) / 256)
#define ORDER_SZ (Nn + 176)                // buckets padded to x16 (11*15=165 max pad); /16 exact
#define NB_MF (ORDER_SZ / 16)              // block = 16 slots (degree-uniform), 4 waves
#define NB_RG (Nn / 16)                    // block = 4 waves; 16 nodes/block (MFMA tile)
#define NB_RELSEG (Ne / 256)               // 3125 edge blocks
#define NB_EMBED (Nn / 4)                  // 12500 embed blocks
#define WT_PER_LAYER (Hd * 5 * Hd)         // 20480 halves: [64 cols][320 k]
#define MFWT_PER_LAYER ((MAXD + 1) * Hd * 2 * Hd)  // 90112 halves: [d][64 cols][128 k]
#define PREP_TOTAL (2 * WT_PER_LAYER + 2 * MFWT_PER_LAYER)

typedef _Float16 f16x8 __attribute__((ext_vector_type(8)));
typedef float f32x4 __attribute__((ext_vector_type(4)));

__device__ __forceinline__ float reluf(float v) { return v > 0.f ? v : 0.f; }
__device__ __forceinline__ int rfl(int v) { return __builtin_amdgcn_readfirstlane(v); }

// ---- FUSED: per-edge relation argmax/histogram/rank  +  embedding lookup ----
__global__ void k_rel_emb(const float4* __restrict__ ea, const int* __restrict__ eidx,
                          int* __restrict__ seg, int* __restrict__ rank,
                          int* __restrict__ cnt,
                          const float* __restrict__ x, const float* __restrict__ emb,
                          __half* __restrict__ h16) {
    if (blockIdx.x < NB_RELSEG) {
        int e = blockIdx.x * 256 + threadIdx.x;     // grid sized exactly: e < Ne
        float4 a = ea[e];
        int bi = 0; float bv = a.x;
        if (a.y > bv) { bv = a.y; bi = 1; }
        if (a.z > bv) { bv = a.z; bi = 2; }
        if (a.w > bv) { bv = a.w; bi = 3; }
        int s = eidx[Ne + e] * Rr + bi;
        seg[e] = s;
        rank[e] = atomicAdd(&cnt[s], 1);
    } else {
        int wave = ((blockIdx.x - NB_RELSEG) * 256 + threadIdx.x) >> 6;  // < Nn
        int lane = threadIdx.x & 63;
        float v = (lane < NFd) ? x[(size_t)wave * NFd + lane] : -1e30f;
        int idx = lane;
        #pragma unroll
        for (int off = 16; off >= 1; off >>= 1) {
            float ov = __shfl_down(v, off);
            int oi = __shfl_down(idx, off);
            if (ov > v || (ov == v && oi < idx)) { v = ov; idx = oi; }
        }
        idx = __shfl(idx, 0);
        float hv = reluf(emb[(size_t)idx * Hd + lane]);
        h16[(size_t)wave * Hd + lane] = __float2half(hv);
    }
}

// ---- prep: fp16 transposed-stacked weights for both MFMA transforms ----
__global__ void k_prep(const float* __restrict__ w0, const float* __restrict__ r0,
                       const float* __restrict__ w1, const float* __restrict__ r1,
                       const float* __restrict__ wl0, const float* __restrict__ wr0,
                       const float* __restrict__ wl1, const float* __restrict__ wr1,
                       __half* __restrict__ wt, __half* __restrict__ mfwt) {
    int idx = blockIdx.x * 256 + threadIdx.x;
    if (idx < 2 * WT_PER_LAYER) {
        int b = idx / WT_PER_LAYER;
        int rem = idx % WT_PER_LAYER;
        int c = rem / 320;
        int k = rem % 320;
        const float* W  = b ? w1 : w0;
        const float* Rt = b ? r1 : r0;
        float v = (k < 64) ? Rt[k * Hd + c]
                           : W[((size_t)((k - 64) >> 6)) * Hd * Hd + ((k - 64) & 63) * Hd + c];
        wt[idx] = __float2half(v);
    } else if (idx < PREP_TOTAL) {
        int j = idx - 2 * WT_PER_LAYER;
        int b = j / MFWT_PER_LAYER;
        int rem = j % MFWT_PER_LAYER;
        int d = rem / (Hd * 128);
        int r2 = rem % (Hd * 128);
        int c = r2 / 128;
        int k = r2 % 128;
        const float* Wl = b ? wl1 : wl0;
        const float* Wr = b ? wr1 : wr0;
        float v = (k < 64) ? Wl[(size_t)d * Hd * Hd + k * Hd + c]
                           : Wr[(size_t)d * Hd * Hd + (k - 64) * Hd + c];
        mfwt[j] = __float2half(v);
    }
}

// ---- scan level 1 + fused degree histogram ----
__global__ void k_scan1(const int* __restrict__ cnt, int* __restrict__ off,
                        int* __restrict__ bsum, int* __restrict__ bcnt) {
    __shared__ int s[256];
    __shared__ int hist[16];
    int t = threadIdx.x;
    if (t < 16) hist[t] = 0;
    int idx = blockIdx.x * 256 + t;
    int v = (idx < NSEG) ? cnt[idx] : 0;
    s[t] = v;
    __syncthreads();
    if ((t & 3) == 0 && idx < NSEG) {
        int dsum = s[t] + s[t + 1] + s[t + 2] + s[t + 3];
        atomicAdd(&hist[min(dsum, MAXD)], 1);
    }
    #pragma unroll
    for (int o = 1; o < 256; o <<= 1) {
        int x = (t >= o) ? s[t - o] : 0;
        __syncthreads();
        s[t] += x;
        __syncthreads();
    }
    if (idx < NSEG) off[idx] = s[t] - v;            // exclusive
    if (t == 255) bsum[blockIdx.x] = s[255];
    if (t < 16) {
        int h = hist[t];
        if (h > 0) atomicAdd(&bcnt[t], h);
    }
}

// ---- scan level 2 + fused bucket prefix (16-aligned) + order pad-slot writes ----
__global__ void k_scan2(int* __restrict__ bsum, const int* __restrict__ bcnt,
                        int* __restrict__ bbase, int* __restrict__ order) {
    __shared__ int s[1024];
    int t = threadIdx.x;
    int v = (t < SCAN_BLK) ? bsum[t] : 0;
    s[t] = v;
    __syncthreads();
    #pragma unroll
    for (int o = 1; o < 1024; o <<= 1) {
        int x = (t >= o) ? s[t - o] : 0;
        __syncthreads();
        s[t] += x;
        __syncthreads();
    }
    if (t < SCAN_BLK) bsum[t] = s[t] - v;           // exclusive block bases
    if (t == 0) {
        int run = 0;
        for (int d = 0; d <= MAXD; d++) {
            int c = bcnt[d];
            bbase[d] = run;
            int pad = (c + 15) & ~15;               // x16: MFMA tile = degree-uniform
            for (int i = c; i < pad; i++) order[run + i] = -1;
            run += pad;
        }
        for (int i = run; i < ORDER_SZ; i++) order[i] = -1;
    }
}

// ---- FUSED: scan level 3 (final off)  +  degree-bucket scatter ----
__global__ void k_scan3_bucket(int* __restrict__ off, const int* __restrict__ bsum,
                               const int4* __restrict__ cnt4, const int* __restrict__ bbase,
                               int* __restrict__ bfill, int* __restrict__ order) {
    __shared__ int hist[16];
    __shared__ int base[16];
    int t = threadIdx.x;
    if (t < 16) hist[t] = 0;
    __syncthreads();
    int idx = blockIdx.x * 256 + t;
    if (idx == 0) off[NSEG] = Ne;
    if (idx < NSEG) off[idx] = off[idx] + bsum[blockIdx.x];
    int d = 0, rk = 0;
    bool valid = (idx < Nn);
    if (valid) {
        int4 c = cnt4[idx];
        d = min(c.x + c.y + c.z + c.w, MAXD);
        rk = atomicAdd(&hist[d], 1);
    }
    __syncthreads();
    if (t < 16) {
        int h = hist[t];
        base[t] = (h > 0) ? atomicAdd(&bfill[t], h) : 0;
    }
    __syncthreads();
    if (valid) order[bbase[d] + base[d] + rk] = idx | (d << 20);
}

// ---- scatter edges into segment-sorted order: NO atomics (rank precomputed) ----
__global__ void k_scatter(const int* __restrict__ eidx, const int* __restrict__ seg,
                          const int* __restrict__ rank, const int* __restrict__ off,
                          int* __restrict__ sorted_src) {
    int e = blockIdx.x * 256 + threadIdx.x;
    if (e >= Ne) return;
    int pos = off[seg[e]] + rank[e];
    sorted_src[pos] = eidx[e];
}

#define H16(ptr, s) __half2float((ptr)[(size_t)(s) * Hd + lane])

// ---- FUSED RGCN layer: prefix-snapshot gather -> fp16 LDS -> MFMA transform ----
// Boundaries live in LANES (obv), fetched via dynamic __shfl (no scratch).
// fp32 output dropped: downstream consumes only the fp16 shadow.
__global__ __launch_bounds__(256) void k_rgcn_fused(
        const __half* __restrict__ hin16,
        const int* __restrict__ off, const int* __restrict__ ssrc,
        const __half* __restrict__ wt, const float* __restrict__ bias,
        __half* __restrict__ hout16) {
    __shared__ __align__(16) __half alds[16 * 296];  // [node]: rel*72 + k; node stride 296
    int tid = threadIdx.x;
    int wv = tid >> 6, lane = tid & 63;
    int nblk = rfl(blockIdx.x * 16);
    int n0 = nblk + wv * 4;
    // boundaries in lanes: lane k (k<=16) holds off[4*n0+k]; lanes >16 replicate b16
    int obv = off[4 * n0 + min(lane, 16)];
    int cntv = __shfl(obv, lane + 1) - obv;         // lane<16: edges in segment 'lane'
    float ivv = (cntv > 0) ? 1.f / (float)cntv : 0.f;
    int e    = rfl(__shfl(obv, 0));
    int eEnd = rfl(__shfl(obv, 16));

    float acc = 0.f, snap = 0.f;
    int segi = 0;
    int nb = rfl(__shfl(obv, 1));

#define EMIT_SEG do {                                                \
        float d_ = acc - snap; snap = acc;                           \
        float iv_ = __shfl(ivv, segi);                               \
        alds[(wv * 4 + (segi >> 2)) * 296 + (segi & 3) * 72 + lane]  \
            = __float2half(d_ * iv_);                                \
        segi++;                                                      \
        nb = (segi < 16) ? rfl(__shfl(obv, segi + 1)) : 0x7fffffff;  \
    } while (0)

    if (e + 16 <= eEnd) {
        int4 iA = *(const int4*)(ssrc + e);
        int4 iB = *(const int4*)(ssrc + e + 4);
        int4 iC = *(const int4*)(ssrc + e + 8);
        int4 iD = *(const int4*)(ssrc + e + 12);
        while (true) {
            int en = e + 16;
            bool more = (en + 16 <= eEnd);
            int4 jA, jB, jC, jD;
            if (more) {                             // prefetch next chunk's indices
                jA = *(const int4*)(ssrc + en);
                jB = *(const int4*)(ssrc + en + 4);
                jC = *(const int4*)(ssrc + en + 8);
                jD = *(const int4*)(ssrc + en + 12);
            }
            float v0 = H16(hin16, iA.x);
            float v1 = H16(hin16, iA.y);
            float v2 = H16(hin16, iA.z);
            float v3 = H16(hin16, iA.w);
            float v4 = H16(hin16, iB.x);
            float v5 = H16(hin16, iB.y);
            float v6 = H16(hin16, iB.z);
            float v7 = H16(hin16, iB.w);
            float v8 = H16(hin16, iC.x);
            float v9 = H16(hin16, iC.y);
            float vA = H16(hin16, iC.z);
            float vB = H16(hin16, iC.w);
            float vC = H16(hin16, iD.x);
            float vD = H16(hin16, iD.y);
            float vE = H16(hin16, iD.z);
            float vF = H16(hin16, iD.w);
            // ordered prefix adds; boundary checks are wave-uniform compares
            while (e + 0  == nb) EMIT_SEG;  acc += v0;
            while (e + 1  == nb) EMIT_SEG;  acc += v1;
            while (e + 2  == nb) EMIT_SEG;  acc += v2;
            while (e + 3  == nb) EMIT_SEG;  acc += v3;
            while (e + 4  == nb) EMIT_SEG;  acc += v4;
            while (e + 5  == nb) EMIT_SEG;  acc += v5;
            while (e + 6  == nb) EMIT_SEG;  acc += v6;
            while (e + 7  == nb) EMIT_SEG;  acc += v7;
            while (e + 8  == nb) EMIT_SEG;  acc += v8;
            while (e + 9  == nb) EMIT_SEG;  acc += v9;
            while (e + 10 == nb) EMIT_SEG;  acc += vA;
            while (e + 11 == nb) EMIT_SEG;  acc += vB;
            while (e + 12 == nb) EMIT_SEG;  acc += vC;
            while (e + 13 == nb) EMIT_SEG;  acc += vD;
            while (e + 14 == nb) EMIT_SEG;  acc += vE;
            while (e + 15 == nb) EMIT_SEG;  acc += vF;
            e = en;
            if (!more) break;
            iA = jA; iB = jB; iC = jC; iD = jD;
        }
    }
    for (; e < eEnd; e++) {                         // tail (< 16 edges)
        while (e == nb) EMIT_SEG;
        int s = rfl(ssrc[e]);
        acc += H16(hin16, s);
    }
    while (segi < 16) EMIT_SEG;                     // trailing (possibly empty) segments
#undef EMIT_SEG

    __syncthreads();                                // waves share the A tile now

    // ---- MFMA transform: wave wv -> output cols [16wv, 16wv+16), 16 nodes ----
    int rp = lane & 15;
    int g  = lane >> 4;
    const __half* ha = hin16 + (size_t)(nblk + rp) * Hd + 8 * g;
    const __half* ba = wt + (size_t)(wv * 16 + rp) * 320 + 8 * g;
    const __half* aa = alds + rp * 296 + 8 * g;
    f32x4 dacc = {0.f, 0.f, 0.f, 0.f};
    #pragma unroll
    for (int s = 0; s < 10; s++) {                  // k0 = 32*s; a-source matches (32s)
        f16x8 bfrag = *(const f16x8*)(ba + s * 32);
        f16x8 afrag;
        if (s < 2) afrag = *(const f16x8*)(ha + s * 32);
        else       afrag = *(const f16x8*)(aa + ((s - 2) >> 1) * 72 + ((s - 2) & 1) * 32);
        dacc = __builtin_amdgcn_mfma_f32_16x16x32_f16(afrag, bfrag, dacc, 0, 0, 0);
    }
    int c = wv * 16 + rp;
    float bb = bias[c];
    #pragma unroll
    for (int j = 0; j < 4; j++) {
        int row = nblk + g * 4 + j;
        float v = reluf(dacc[j] + bb);
        hout16[(size_t)row * Hd + c] = __float2half(v);   // fp32 store eliminated (dead)
    }
}

// ---- FUSED MFConv layer: fp16 gather -> shared fp16 LDS A-tile -> MFMA ----
// Epilogue writes fp16 shadow (b=0, feeds next layer) OR fp32 (b=1, feeds pool).
__global__ __launch_bounds__(256) void k_mf_fused(
        const __half* __restrict__ hin16,
        const int* __restrict__ off, const int* __restrict__ ssrc,
        const int* __restrict__ order, const __half* __restrict__ mfwt,
        const float* __restrict__ bl,
        float* __restrict__ hout, __half* __restrict__ hout16, int relu_out) {
    __shared__ __align__(16) __half alds[16 * 72];  // 2.25 KB: [slot][k], stride 72
    int tid = threadIdx.x;
    int wv = tid >> 6, lane = tid & 63;
    int blk = rfl(blockIdx.x * 16);
    int ent0 = rfl(order[blk]);
    if (ent0 < 0) return;                           // entire block is pad
    int d = ent0 >> 20;
    for (int i = 0; i < 4; i++) {                   // wave gathers its 4 slots
        int slot = blk + wv * 4 + i;
        int ent = rfl(order[slot]);
        float sum = 0.f;
        if (ent >= 0) {
            int n = ent & 0xFFFFF;
            int e0 = rfl(off[n * Rr]);
            int e4 = rfl(off[n * Rr + Rr]);
            float p0 = 0.f, p1 = 0.f, p2 = 0.f, p3 = 0.f;
            int e = e0;
            for (; e + 16 <= e4; e += 16) {
                const int4 sA = *(const int4*)(ssrc + e);
                const int4 sB = *(const int4*)(ssrc + e + 4);
                const int4 sC = *(const int4*)(ssrc + e + 8);
                const int4 sD = *(const int4*)(ssrc + e + 12);
                p0 += H16(hin16, sA.x) + H16(hin16, sA.y) + H16(hin16, sA.z) + H16(hin16, sA.w);
                p1 += H16(hin16, sB.x) + H16(hin16, sB.y) + H16(hin16, sB.z) + H16(hin16, sB.w);
                p2 += H16(hin16, sC.x) + H16(hin16, sC.y) + H16(hin16, sC.z) + H16(hin16, sC.w);
                p3 += H16(hin16, sD.x) + H16(hin16, sD.y) + H16(hin16, sD.z) + H16(hin16, sD.w);
            }
            for (; e + 4 <= e4; e += 4) {
                const int4 sA = *(const int4*)(ssrc + e);
                p0 += H16(hin16, sA.x) + H16(hin16, sA.y) + H16(hin16, sA.z) + H16(hin16, sA.w);
            }
            for (; e < e4; e++) {
                int s = rfl(ssrc[e]);
                p0 += H16(hin16, s);
            }
            sum = (p0 + p1) + (p2 + p3);
        }
        alds[(wv * 4 + i) * 72 + lane] = __float2half(sum);
    }
    __syncthreads();

    // ---- MFMA: wave wv -> output cols [16wv,16wv+16), rows = 16 tile slots ----
    int rp = lane & 15;
    int g  = lane >> 4;
    int entr = order[blk + rp];                     // per-lane row entry (L2-hot)
    int nr = (entr >= 0) ? (entr & 0xFFFFF) : 0;
    const __half* aa = alds + rp * 72 + 8 * g;
    const __half* ha = hin16 + (size_t)nr * Hd + 8 * g;
    const __half* ba = mfwt + ((size_t)d * Hd + wv * 16 + rp) * 128 + 8 * g;
    f32x4 dacc = {0.f, 0.f, 0.f, 0.f};
    #pragma unroll
    for (int s = 0; s < 4; s++) {                   // K=128: k<64 agg@Wl, k>=64 h@Wr
        f16x8 bfrag = *(const f16x8*)(ba + s * 32);
        f16x8 afrag = (s < 2) ? *(const f16x8*)(aa + s * 32)
                              : *(const f16x8*)(ha + (s - 2) * 32);
        dacc = __builtin_amdgcn_mfma_f32_16x16x32_f16(afrag, bfrag, dacc, 0, 0, 0);
    }
    int c = wv * 16 + rp;
    float bb = bl[d * Hd + c];
    #pragma unroll
    for (int j = 0; j < 4; j++) {
        int entw = order[blk + g * 4 + j];
        if (entw >= 0) {
            int n = entw & 0xFFFFF;
            float v = dacc[j] + bb;
            if (relu_out) hout16[(size_t)n * Hd + c] = __float2half(reluf(v));
            else          hout[(size_t)n * Hd + c] = v;   // pool path (layer 1)
        }
    }
}

// ---- global add pool (batch_idx is sorted -> mostly single fused atomic) ----
__global__ void k_pool(const float* __restrict__ h, const int* __restrict__ batch,
                       float* __restrict__ g) {
    int wave = rfl((blockIdx.x * 256 + threadIdx.x) >> 6);
    int lane = threadIdx.x & 63;
    int n0 = wave * 4;
    if (n0 >= Nn) return;
    int b0 = batch[n0], b1 = batch[n0 + 1], b2 = batch[n0 + 2], b3 = batch[n0 + 3];
    float v0 = h[(size_t)n0 * Hd + lane];
    float v1 = h[(size_t)(n0 + 1) * Hd + lane];
    float v2 = h[(size_t)(n0 + 2) * Hd + lane];
    float v3 = h[(size_t)(n0 + 3) * Hd + lane];
    if (b0 == b1 && b0 == b2 && b0 == b3) {
        unsafeAtomicAdd(&g[(size_t)b0 * Hd + lane], v0 + v1 + v2 + v3);
    } else {
        unsafeAtomicAdd(&g[(size_t)b0 * Hd + lane], v0);
        unsafeAtomicAdd(&g[(size_t)b1 * Hd + lane], v1);
        unsafeAtomicAdd(&g[(size_t)b2 * Hd + lane], v2);
        unsafeAtomicAdd(&g[(size_t)b3 * Hd + lane], v3);
    }
}

// ---- head: relu(g@lin1+b1)@lin2+b2, one wave per graph ----
__global__ void k_head(const float* __restrict__ g, const float* __restrict__ w1,
                       const float* __restrict__ b1, const float* __restrict__ w2,
                       const float* __restrict__ b2, float* __restrict__ out) {
    __shared__ float t[4][Hd];
    int wv = threadIdx.x >> 6;
    int lane = threadIdx.x & 63;
    int gi = blockIdx.x * 4 + wv;
    float acc = b1[lane];
    for (int k = 0; k < Hd; k++) acc += g[(size_t)gi * Hd + k] * w1[k * Hd + lane];
    t[wv][lane] = reluf(acc);
    __syncthreads();
    if (lane < Od) {
        float o = b2[lane];
        for (int k = 0; k < Hd; k++) o += t[wv][k] * w2[k * Od + lane];
        out[(size_t)gi * Od + lane] = o;
    }
}

extern "C" void kernel_launch(void* const* d_in, const int* in_sizes, int n_in,
                              void* d_out, int out_size, void* d_ws, size_t ws_size,
                              hipStream_t stream) {
    const float* x      = (const float*)d_in[0];
    const float* ea     = (const float*)d_in[1];
    const int*   eidx   = (const int*)d_in[2];
    const int*   batch  = (const int*)d_in[3];
    const float* emb    = (const float*)d_in[4];
    const float* lin1_w = (const float*)d_in[5];
    const float* lin1_b = (const float*)d_in[6];
    const float* lin2_w = (const float*)d_in[7];
    const float* lin2_b = (const float*)d_in[8];
    const float* rgcn_w[2]    = {(const float*)d_in[9],  (const float*)d_in[15]};
    const float* rgcn_root[2] = {(const float*)d_in[10], (const float*)d_in[16]};
    const float* rgcn_b[2]    = {(const float*)d_in[11], (const float*)d_in[17]};
    const float* mf_wl[2]     = {(const float*)d_in[12], (const float*)d_in[18]};
    const float* mf_bl[2]     = {(const float*)d_in[13], (const float*)d_in[19]};
    const float* mf_wr[2]     = {(const float*)d_in[14], (const float*)d_in[20]};

    char* p = (char*)d_ws;
    float* h32   = (float*)p; p += sizeof(float) * (size_t)Nn * Hd;
    __half* h16a = (__half*)p; p += sizeof(__half) * (size_t)Nn * Hd;
    __half* h16b = (__half*)p; p += sizeof(__half) * (size_t)Nn * Hd;
    float* gbuf  = (float*)p; p += sizeof(float) * (size_t)Ng * Hd;
    __half* wt16 = (__half*)p; p += sizeof(__half) * (size_t)2 * WT_PER_LAYER;
    __half* mfwt16 = (__half*)p; p += sizeof(__half) * (size_t)2 * MFWT_PER_LAYER;
    int* seg     = (int*)p;   p += sizeof(int) * (size_t)Ne;
    int* rank    = (int*)p;   p += sizeof(int) * (size_t)Ne;
    int* ssrc    = (int*)p;   p += sizeof(int) * (size_t)Ne;
    int* cnt     = (int*)p;   p += sizeof(int) * (size_t)NSEG;  // contiguous with bcnt/bfill
    int* bcnt    = (int*)p;   p += sizeof(int) * 16;
    int* bfill   = (int*)p;   p += sizeof(int) * 16;
    int* off     = (int*)p;   p += sizeof(int) * (size_t)(NSEG + 1);
    int* bsum    = (int*)p;   p += sizeof(int) * 1024;
    int* bbase   = (int*)p;   p += sizeof(int) * 16;
    int* order   = (int*)p;   p += sizeof(int) * (size_t)ORDER_SZ;

    hipMemsetAsync(cnt, 0, sizeof(int) * ((size_t)NSEG + 32), stream);
    hipMemsetAsync(gbuf, 0, sizeof(float) * (size_t)Ng * Hd, stream);

    k_prep<<<(PREP_TOTAL + 255) / 256, 256, 0, stream>>>(
        rgcn_w[0], rgcn_root[0], rgcn_w[1], rgcn_root[1],
        mf_wl[0], mf_wr[0], mf_wl[1], mf_wr[1], wt16, mfwt16);
    k_rel_emb<<<NB_RELSEG + NB_EMBED, 256, 0, stream>>>((const float4*)ea, eidx, seg, rank,
                                                        cnt, x, emb, h16a);
    k_scan1<<<SCAN_BLK, 256, 0, stream>>>(cnt, off, bsum, bcnt);
    k_scan2<<<1, 1024, 0, stream>>>(bsum, bcnt, bbase, order);
    k_scan3_bucket<<<SCAN_BLK, 256, 0, stream>>>(off, bsum, (const int4*)cnt, bbase,
                                                 bfill, order);
    k_scatter<<<Ne / 256, 256, 0, stream>>>(eidx, seg, rank, off, ssrc);

    __half* hin16 = h16a;  __half* hout16 = h16b;
    for (int b = 0; b < 2; b++) {
        k_rgcn_fused<<<NB_RG, 256, 0, stream>>>(hin16, off, ssrc, wt16 + b * WT_PER_LAYER,
                                                rgcn_b[b], hout16);
        k_mf_fused<<<NB_MF, 256, 0, stream>>>(hout16, off, ssrc, order,
                                              mfwt16 + b * MFWT_PER_LAYER, mf_bl[b],
                                              h32, hin16, b == 0 ? 1 : 0);
        // b=0: mf writes fp16 shadow into hin16 (next layer); b=1: fp32 into h32 (pool)
    }
    k_pool<<<Nn / 16, 256, 0, stream>>>(h32, batch, gbuf);
    k_head<<<Ng / 4, 256, 0, stream>>>(gbuf, lin1_w, lin1_b, lin2_w, lin2_b, (float*)d_out);
}

// Round 9
// 331.743 us; speedup vs baseline: 1.1007x; 1.0327x over previous
//
#include <hip/hip_runtime.h>
#include <hip/hip_fp16.h>
#include <cstdint>
#include <cstddef>

#define Nn 50000
#define Ne 800000
#define Ng 1024
#define NFd 32
#define Rr 4
#define Hd 64
#define Od 16
#define MAXD 10
#define NSEG (Nn * Rr)
#define SCAN_BLK ((NSEG + 255) / 256)
#define ORDER_SZ (Nn + 176)                // buckets padded to x16 (11*15=165 max pad); /16 exact
#define NB_MF (ORDER_SZ / 16)              // block = 16 slots (degree-uniform), 4 waves
#define NB_RG (Nn / 16)                    // block = 4 waves; 16 nodes/block (MFMA tile)
#define NB_RELSEG (Ne / 256)               // 3125 edge blocks
#define NB_EMBED (Nn / 8)                  // 6250 embed blocks (2 nodes/wave)
#define WT_PER_LAYER (Hd * 5 * Hd)         // 20480 halves: [64 cols][320 k]
#define MFWT_PER_LAYER ((MAXD + 1) * Hd * 2 * Hd)  // 90112 halves: [d][64 cols][128 k]
#define PREP_TOTAL (2 * WT_PER_LAYER + 2 * MFWT_PER_LAYER)

typedef _Float16 f16x8 __attribute__((ext_vector_type(8)));
typedef float f32x4 __attribute__((ext_vector_type(4)));

__device__ __forceinline__ float reluf(float v) { return v > 0.f ? v : 0.f; }
__device__ __forceinline__ int rfl(int v) { return __builtin_amdgcn_readfirstlane(v); }

// ---- FUSED: per-edge relation argmax/rank (atomic hidden under embed work)
//      + embedding lookup (2 nodes/wave, float2/half2 I/O) ----
__global__ void k_rel_emb(const float4* __restrict__ ea, const int* __restrict__ eidx,
                          int* __restrict__ seg, int* __restrict__ rank,
                          int* __restrict__ cnt,
                          const float* __restrict__ x, const float* __restrict__ emb,
                          __half* __restrict__ h16) {
    if (blockIdx.x < NB_RELSEG) {
        int e = blockIdx.x * 256 + threadIdx.x;     // grid sized exactly: e < Ne
        float4 a = ea[e];
        int bi = 0; float bv = a.x;
        if (a.y > bv) { bv = a.y; bi = 1; }
        if (a.z > bv) { bv = a.z; bi = 2; }
        if (a.w > bv) { bv = a.w; bi = 3; }
        int s = eidx[Ne + e] * Rr + bi;
        seg[e] = s;
        rank[e] = atomicAdd(&cnt[s], 1);
    } else {
        int wave = ((blockIdx.x - NB_RELSEG) * 256 + threadIdx.x) >> 6;  // < Nn/2
        int lane = threadIdx.x & 63;
        int h = lane >> 5, q = lane & 31;
        int node = wave * 2 + h;
        float v = x[(size_t)node * NFd + q];
        int idx = q;
        #pragma unroll
        for (int o = 16; o >= 1; o >>= 1) {         // xor-butterfly within half-wave
            float ov = __shfl_xor(v, o);
            int oi = __shfl_xor(idx, o);
            if (ov > v || (ov == v && oi < idx)) { v = ov; idx = oi; }
        }
        const float2* e2 = (const float2*)(emb + (size_t)idx * Hd);
        float2 ev = e2[q];
        ((__half2*)h16)[(size_t)node * 32 + q] =
            __floats2half2_rn(reluf(ev.x), reluf(ev.y));
    }
}

// ---- prep: fp16 transposed-stacked weights for both MFMA transforms ----
__global__ void k_prep(const float* __restrict__ w0, const float* __restrict__ r0,
                       const float* __restrict__ w1, const float* __restrict__ r1,
                       const float* __restrict__ wl0, const float* __restrict__ wr0,
                       const float* __restrict__ wl1, const float* __restrict__ wr1,
                       __half* __restrict__ wt, __half* __restrict__ mfwt) {
    int idx = blockIdx.x * 256 + threadIdx.x;
    if (idx < 2 * WT_PER_LAYER) {
        int b = idx / WT_PER_LAYER;
        int rem = idx % WT_PER_LAYER;
        int c = rem / 320;
        int k = rem % 320;
        const float* W  = b ? w1 : w0;
        const float* Rt = b ? r1 : r0;
        float v = (k < 64) ? Rt[k * Hd + c]
                           : W[((size_t)((k - 64) >> 6)) * Hd * Hd + ((k - 64) & 63) * Hd + c];
        wt[idx] = __float2half(v);
    } else if (idx < PREP_TOTAL) {
        int j = idx - 2 * WT_PER_LAYER;
        int b = j / MFWT_PER_LAYER;
        int rem = j % MFWT_PER_LAYER;
        int d = rem / (Hd * 128);
        int r2 = rem % (Hd * 128);
        int c = r2 / 128;
        int k = r2 % 128;
        const float* Wl = b ? wl1 : wl0;
        const float* Wr = b ? wr1 : wr0;
        float v = (k < 64) ? Wl[(size_t)d * Hd * Hd + k * Hd + c]
                           : Wr[(size_t)d * Hd * Hd + (k - 64) * Hd + c];
        mfwt[j] = __float2half(v);
    }
}

// ---- scan level 1 + fused degree histogram ----
__global__ void k_scan1(const int* __restrict__ cnt, int* __restrict__ off,
                        int* __restrict__ bsum, int* __restrict__ bcnt) {
    __shared__ int s[256];
    __shared__ int hist[16];
    int t = threadIdx.x;
    if (t < 16) hist[t] = 0;
    int idx = blockIdx.x * 256 + t;
    int v = (idx < NSEG) ? cnt[idx] : 0;
    s[t] = v;
    __syncthreads();
    if ((t & 3) == 0 && idx < NSEG) {
        int dsum = s[t] + s[t + 1] + s[t + 2] + s[t + 3];
        atomicAdd(&hist[min(dsum, MAXD)], 1);
    }
    #pragma unroll
    for (int o = 1; o < 256; o <<= 1) {
        int x = (t >= o) ? s[t - o] : 0;
        __syncthreads();
        s[t] += x;
        __syncthreads();
    }
    if (idx < NSEG) off[idx] = s[t] - v;            // exclusive
    if (t == 255) bsum[blockIdx.x] = s[255];
    if (t < 16) {
        int h = hist[t];
        if (h > 0) atomicAdd(&bcnt[t], h);
    }
}

// ---- scan level 2 + fused bucket prefix (16-aligned) + order pad-slot writes ----
__global__ void k_scan2(int* __restrict__ bsum, const int* __restrict__ bcnt,
                        int* __restrict__ bbase, int* __restrict__ order) {
    __shared__ int s[1024];
    int t = threadIdx.x;
    int v = (t < SCAN_BLK) ? bsum[t] : 0;
    s[t] = v;
    __syncthreads();
    #pragma unroll
    for (int o = 1; o < 1024; o <<= 1) {
        int x = (t >= o) ? s[t - o] : 0;
        __syncthreads();
        s[t] += x;
        __syncthreads();
    }
    if (t < SCAN_BLK) bsum[t] = s[t] - v;           // exclusive block bases
    if (t == 0) {
        int run = 0;
        for (int d = 0; d <= MAXD; d++) {
            int c = bcnt[d];
            bbase[d] = run;
            int pad = (c + 15) & ~15;               // x16: MFMA tile = degree-uniform
            for (int i = c; i < pad; i++) order[run + i] = -1;
            run += pad;
        }
        for (int i = run; i < ORDER_SZ; i++) order[i] = -1;
    }
}

// ---- FUSED: scan level 3 (final off)  +  degree-bucket scatter ----
__global__ void k_scan3_bucket(int* __restrict__ off, const int* __restrict__ bsum,
                               const int4* __restrict__ cnt4, const int* __restrict__ bbase,
                               int* __restrict__ bfill, int* __restrict__ order) {
    __shared__ int hist[16];
    __shared__ int base[16];
    int t = threadIdx.x;
    if (t < 16) hist[t] = 0;
    __syncthreads();
    int idx = blockIdx.x * 256 + t;
    if (idx == 0) off[NSEG] = Ne;
    if (idx < NSEG) off[idx] = off[idx] + bsum[blockIdx.x];
    int d = 0, rk = 0;
    bool valid = (idx < Nn);
    if (valid) {
        int4 c = cnt4[idx];
        d = min(c.x + c.y + c.z + c.w, MAXD);
        rk = atomicAdd(&hist[d], 1);
    }
    __syncthreads();
    if (t < 16) {
        int h = hist[t];
        base[t] = (h > 0) ? atomicAdd(&bfill[t], h) : 0;
    }
    __syncthreads();
    if (valid) order[bbase[d] + base[d] + rk] = idx | (d << 20);
}

// ---- scatter edges into segment-sorted order: NO atomics (rank precomputed) ----
__global__ void k_scatter(const int* __restrict__ eidx, const int* __restrict__ seg,
                          const int* __restrict__ rank, const int* __restrict__ off,
                          int* __restrict__ sorted_src) {
    int e = blockIdx.x * 256 + threadIdx.x;
    if (e >= Ne) return;
    int pos = off[seg[e]] + rank[e];
    sorted_src[pos] = eidx[e];
}

// ---- FUSED RGCN layer: paired-edge fp16 gather (4B/lane) -> MFMA transform ----
// Half-wave h processes edge t+h of each pair; lane q=lane&31 holds cols {2q,2q+1}.
// Segment sums via per-half prefix snapshots; odd (mid-pair) boundaries subtract
// half1's just-added value (exact). Emits are wave-uniform scalar branches.
__global__ __launch_bounds__(256) void k_rgcn_fused(
        const __half* __restrict__ hin16,
        const int* __restrict__ off, const int* __restrict__ ssrc,
        const __half* __restrict__ wt, const float* __restrict__ bias,
        __half* __restrict__ hout16) {
    __shared__ __align__(16) __half alds[16 * 296];  // [node]: rel*72 + k; node stride 296
    int tid = threadIdx.x;
    int wv = tid >> 6, lane = tid & 63;
    int h = lane >> 5, q = lane & 31;
    int nblk = rfl(blockIdx.x * 16);
    int n0 = nblk + wv * 4;
    int obv = off[4 * n0 + min(lane, 16)];          // boundaries live in lanes
    int cntv = __shfl(obv, lane + 1) - obv;
    float ivv = (cntv > 0) ? 1.f / (float)cntv : 0.f;
    int e    = rfl(__shfl(obv, 0));
    int eEnd = rfl(__shfl(obv, 16));
    const __half2* hp = (const __half2*)hin16;      // row = 32 half2

    float ax = 0.f, ay = 0.f;                       // running prefix (per half)
    float px = 0.f, py = 0.f;                       // snapshot
    float vx = 0.f, vy = 0.f;                       // half's most recent added value
    int segi = 0;
    int nb = rfl(__shfl(obv, 1));

#define EMIT(SUB) do {                                               \
        float dx = ax - px, dy = ay - py;                            \
        float ox = ((SUB) && h) ? vx : 0.f;                          \
        float oy = ((SUB) && h) ? vy : 0.f;                          \
        dx -= ox; dy -= oy;                                          \
        dx += __shfl_xor(dx, 32); dy += __shfl_xor(dy, 32);          \
        float iv_ = __shfl(ivv, segi);                               \
        if (lane < 32)                                               \
            *(__half2*)&alds[(wv * 4 + (segi >> 2)) * 296            \
                             + (segi & 3) * 72 + 2 * q]              \
                = __floats2half2_rn(dx * iv_, dy * iv_);             \
        px = ax - ox; py = ay - oy;                                  \
        segi++;                                                      \
        nb = (segi < 16) ? rfl(__shfl(obv, segi + 1)) : 0x7fffffff;  \
    } while (0)

#define PSTEP(dj, t0) {                                              \
        while ((t0) == nb) EMIT(0);                                  \
        float2 f_ = __half22float2(dj);                              \
        vx = f_.x; vy = f_.y; ax += f_.x; ay += f_.y;                \
        while ((t0) + 1 == nb) EMIT(1); }

    if (e + 16 <= eEnd) {
        int4 iA = *(const int4*)(ssrc + e);
        int4 iB = *(const int4*)(ssrc + e + 4);
        int4 iC = *(const int4*)(ssrc + e + 8);
        int4 iD = *(const int4*)(ssrc + e + 12);
        while (true) {
            int s0 = h ? iA.y : iA.x;               // pair j: edges e+2j, e+2j+1
            int s1 = h ? iA.w : iA.z;
            int s2 = h ? iB.y : iB.x;
            int s3 = h ? iB.w : iB.z;
            int s4 = h ? iC.y : iC.x;
            int s5 = h ? iC.w : iC.z;
            int s6 = h ? iD.y : iD.x;
            int s7 = h ? iD.w : iD.z;
            __half2 d0 = hp[s0 * 32 + q];           // 8 paired loads in flight
            __half2 d1 = hp[s1 * 32 + q];
            __half2 d2 = hp[s2 * 32 + q];
            __half2 d3 = hp[s3 * 32 + q];
            __half2 d4 = hp[s4 * 32 + q];
            __half2 d5 = hp[s5 * 32 + q];
            __half2 d6 = hp[s6 * 32 + q];
            __half2 d7 = hp[s7 * 32 + q];
            int en = e + 16;
            bool more = (en + 16 <= eEnd);
            int4 jA, jB, jC, jD;
            if (more) {                             // prefetch next chunk's indices
                jA = *(const int4*)(ssrc + en);
                jB = *(const int4*)(ssrc + en + 4);
                jC = *(const int4*)(ssrc + en + 8);
                jD = *(const int4*)(ssrc + en + 12);
            }
            PSTEP(d0, e + 0)  PSTEP(d1, e + 2)  PSTEP(d2, e + 4)  PSTEP(d3, e + 6)
            PSTEP(d4, e + 8)  PSTEP(d5, e + 10) PSTEP(d6, e + 12) PSTEP(d7, e + 14)
            e = en;
            if (!more) break;
            iA = jA; iB = jB; iC = jC; iD = jD;
        }
    }
    for (; e + 2 <= eEnd; e += 2) {                 // tail pairs
        while (e == nb) EMIT(0);
        int sa = rfl(ssrc[e]), sb = rfl(ssrc[e + 1]);
        int s = h ? sb : sa;
        float2 f = __half22float2(hp[s * 32 + q]);
        vx = f.x; vy = f.y; ax += f.x; ay += f.y;
        while (e + 1 == nb) EMIT(1);
    }
    if (e < eEnd) {                                 // final single edge (half0 only)
        while (e == nb) EMIT(0);
        int sa = rfl(ssrc[e]);
        float2 f = __half22float2(hp[sa * 32 + q]);
        if (h) { f.x = 0.f; f.y = 0.f; }
        ax += f.x; ay += f.y;
        e++;
    }
    while (segi < 16) EMIT(0);                      // drain (no subtraction needed)
#undef PSTEP
#undef EMIT

    __syncthreads();                                // waves share the A tile now

    // ---- MFMA transform: wave wv -> output cols [16wv, 16wv+16), 16 nodes ----
    int rp = lane & 15;
    int g  = lane >> 4;
    const __half* ha = hin16 + (size_t)(nblk + rp) * Hd + 8 * g;
    const __half* ba = wt + (size_t)(wv * 16 + rp) * 320 + 8 * g;
    const __half* aa = alds + rp * 296 + 8 * g;
    f32x4 dacc = {0.f, 0.f, 0.f, 0.f};
    #pragma unroll
    for (int s = 0; s < 10; s++) {                  // k0 = 32*s; a-source matches (32s)
        f16x8 bfrag = *(const f16x8*)(ba + s * 32);
        f16x8 afrag;
        if (s < 2) afrag = *(const f16x8*)(ha + s * 32);
        else       afrag = *(const f16x8*)(aa + ((s - 2) >> 1) * 72 + ((s - 2) & 1) * 32);
        dacc = __builtin_amdgcn_mfma_f32_16x16x32_f16(afrag, bfrag, dacc, 0, 0, 0);
    }
    int c = wv * 16 + rp;
    float bb = bias[c];
    #pragma unroll
    for (int j = 0; j < 4; j++) {
        int row = nblk + g * 4 + j;
        float v = reluf(dacc[j] + bb);
        hout16[(size_t)row * Hd + c] = __float2half(v);   // fp32 store eliminated (dead)
    }
}

// ---- FUSED MFConv layer: 4-group fp16 gather (8B/lane) -> LDS -> MFMA ----
// Lane group g2=lane>>4 processes edge 4j+g2; lane q4=lane&15 holds cols 4q4..4q4+3.
// Epilogue writes fp16 shadow (b=0, feeds next layer) OR fp32 (b=1, feeds pool).
__global__ __launch_bounds__(256) void k_mf_fused(
        const __half* __restrict__ hin16,
        const int* __restrict__ off, const int* __restrict__ ssrc,
        const int* __restrict__ order, const __half* __restrict__ mfwt,
        const float* __restrict__ bl,
        float* __restrict__ hout, __half* __restrict__ hout16, int relu_out) {
    __shared__ __align__(16) __half alds[16 * 72];  // 2.25 KB: [slot][k], stride 72
    int tid = threadIdx.x;
    int wv = tid >> 6, lane = tid & 63;
    int g2 = lane >> 4, q4 = lane & 15;
    int blk = rfl(blockIdx.x * 16);
    int ent0 = rfl(order[blk]);
    if (ent0 < 0) return;                           // entire block is pad
    int d = ent0 >> 20;
    const uint2* hp2 = (const uint2*)hin16;         // row = 16 uint2 (8B = 4 halves)

#define SEL4(v4) ((g2 & 2) ? ((g2 & 1) ? (v4).w : (v4).z) : ((g2 & 1) ? (v4).y : (v4).x))
#define ACC8(dw) { float2 f_ = __half22float2(*(__half2*)&(dw).x);   \
                   float2 g_ = __half22float2(*(__half2*)&(dw).y);   \
                   a0 += f_.x; a1 += f_.y; a2 += g_.x; a3 += g_.y; }

    for (int i = 0; i < 4; i++) {                   // wave gathers its 4 slots
        int slot = blk + wv * 4 + i;
        int ent = rfl(order[slot]);
        float a0 = 0.f, a1 = 0.f, a2 = 0.f, a3 = 0.f;
        if (ent >= 0) {
            int n = ent & 0xFFFFF;
            int e0 = rfl(off[n * Rr]);
            int e4 = rfl(off[n * Rr + Rr]);
            int e = e0;
            for (; e + 16 <= e4; e += 16) {         // 16 edges = 4 quad-instructions
                int4 iA = *(const int4*)(ssrc + e);
                int4 iB = *(const int4*)(ssrc + e + 4);
                int4 iC = *(const int4*)(ssrc + e + 8);
                int4 iD = *(const int4*)(ssrc + e + 12);
                int sA = SEL4(iA), sB = SEL4(iB), sC = SEL4(iC), sD = SEL4(iD);
                uint2 dA = hp2[(size_t)sA * 16 + q4];
                uint2 dB = hp2[(size_t)sB * 16 + q4];
                uint2 dC = hp2[(size_t)sC * 16 + q4];
                uint2 dD = hp2[(size_t)sD * 16 + q4];
                ACC8(dA) ACC8(dB) ACC8(dC) ACC8(dD)
            }
            for (; e + 4 <= e4; e += 4) {
                int4 iA = *(const int4*)(ssrc + e);
                int sA = SEL4(iA);
                uint2 dA = hp2[(size_t)sA * 16 + q4];
                ACC8(dA)
            }
            int rem = e4 - e;
            if (rem > 0) {                          // masked final quad (per-lane s)
                int idxe = e + g2;
                int sl = ssrc[(idxe < e4) ? idxe : (e4 - 1)];
                uint2 dA = hp2[(size_t)sl * 16 + q4];
                float2 f = __half22float2(*(__half2*)&dA.x);
                float2 g = __half22float2(*(__half2*)&dA.y);
                if (idxe >= e4) { f.x = 0.f; f.y = 0.f; g.x = 0.f; g.y = 0.f; }
                a0 += f.x; a1 += f.y; a2 += g.x; a3 += g.y;
            }
        }
        a0 += __shfl_xor(a0, 16); a0 += __shfl_xor(a0, 32);   // combine 4 groups
        a1 += __shfl_xor(a1, 16); a1 += __shfl_xor(a1, 32);
        a2 += __shfl_xor(a2, 16); a2 += __shfl_xor(a2, 32);
        a3 += __shfl_xor(a3, 16); a3 += __shfl_xor(a3, 32);
        if (lane < 16) {
            __half2* dst = (__half2*)&alds[(wv * 4 + i) * 72 + 4 * q4];
            dst[0] = __floats2half2_rn(a0, a1);
            dst[1] = __floats2half2_rn(a2, a3);
        }
    }
#undef SEL4
#undef ACC8
    __syncthreads();

    // ---- MFMA: wave wv -> output cols [16wv,16wv+16), rows = 16 tile slots ----
    int rp = lane & 15;
    int g  = lane >> 4;
    int entr = order[blk + rp];                     // per-lane row entry (L2-hot)
    int nr = (entr >= 0) ? (entr & 0xFFFFF) : 0;
    const __half* aa = alds + rp * 72 + 8 * g;
    const __half* ha = hin16 + (size_t)nr * Hd + 8 * g;
    const __half* ba = mfwt + ((size_t)d * Hd + wv * 16 + rp) * 128 + 8 * g;
    f32x4 dacc = {0.f, 0.f, 0.f, 0.f};
    #pragma unroll
    for (int s = 0; s < 4; s++) {                   // K=128: k<64 agg@Wl, k>=64 h@Wr
        f16x8 bfrag = *(const f16x8*)(ba + s * 32);
        f16x8 afrag = (s < 2) ? *(const f16x8*)(aa + s * 32)
                              : *(const f16x8*)(ha + (s - 2) * 32);
        dacc = __builtin_amdgcn_mfma_f32_16x16x32_f16(afrag, bfrag, dacc, 0, 0, 0);
    }
    int c = wv * 16 + rp;
    float bb = bl[d * Hd + c];
    #pragma unroll
    for (int j = 0; j < 4; j++) {
        int entw = order[blk + g * 4 + j];
        if (entw >= 0) {
            int n = entw & 0xFFFFF;
            float v = dacc[j] + bb;
            if (relu_out) hout16[(size_t)n * Hd + c] = __float2half(reluf(v));
            else          hout[(size_t)n * Hd + c] = v;   // pool path (layer 1)
        }
    }
}

// ---- global add pool (batch_idx is sorted -> mostly single fused atomic) ----
__global__ void k_pool(const float* __restrict__ h, const int* __restrict__ batch,
                       float* __restrict__ g) {
    int wave = rfl((blockIdx.x * 256 + threadIdx.x) >> 6);
    int lane = threadIdx.x & 63;
    int n0 = wave * 4;
    if (n0 >= Nn) return;
    int b0 = batch[n0], b1 = batch[n0 + 1], b2 = batch[n0 + 2], b3 = batch[n0 + 3];
    float v0 = h[(size_t)n0 * Hd + lane];
    float v1 = h[(size_t)(n0 + 1) * Hd + lane];
    float v2 = h[(size_t)(n0 + 2) * Hd + lane];
    float v3 = h[(size_t)(n0 + 3) * Hd + lane];
    if (b0 == b1 && b0 == b2 && b0 == b3) {
        unsafeAtomicAdd(&g[(size_t)b0 * Hd + lane], v0 + v1 + v2 + v3);
    } else {
        unsafeAtomicAdd(&g[(size_t)b0 * Hd + lane], v0);
        unsafeAtomicAdd(&g[(size_t)b1 * Hd + lane], v1);
        unsafeAtomicAdd(&g[(size_t)b2 * Hd + lane], v2);
        unsafeAtomicAdd(&g[(size_t)b3 * Hd + lane], v3);
    }
}

// ---- head: relu(g@lin1+b1)@lin2+b2, one wave per graph ----
__global__ void k_head(const float* __restrict__ g, const float* __restrict__ w1,
                       const float* __restrict__ b1, const float* __restrict__ w2,
                       const float* __restrict__ b2, float* __restrict__ out) {
    __shared__ float t[4][Hd];
    int wv = threadIdx.x >> 6;
    int lane = threadIdx.x & 63;
    int gi = blockIdx.x * 4 + wv;
    float acc = b1[lane];
    for (int k = 0; k < Hd; k++) acc += g[(size_t)gi * Hd + k] * w1[k * Hd + lane];
    t[wv][lane] = reluf(acc);
    __syncthreads();
    if (lane < Od) {
        float o = b2[lane];
        for (int k = 0; k < Hd; k++) o += t[wv][k] * w2[k * Od + lane];
        out[(size_t)gi * Od + lane] = o;
    }
}

extern "C" void kernel_launch(void* const* d_in, const int* in_sizes, int n_in,
                              void* d_out, int out_size, void* d_ws, size_t ws_size,
                              hipStream_t stream) {
    const float* x      = (const float*)d_in[0];
    const float* ea     = (const float*)d_in[1];
    const int*   eidx   = (const int*)d_in[2];
    const int*   batch  = (const int*)d_in[3];
    const float* emb    = (const float*)d_in[4];
    const float* lin1_w = (const float*)d_in[5];
    const float* lin1_b = (const float*)d_in[6];
    const float* lin2_w = (const float*)d_in[7];
    const float* lin2_b = (const float*)d_in[8];
    const float* rgcn_w[2]    = {(const float*)d_in[9],  (const float*)d_in[15]};
    const float* rgcn_root[2] = {(const float*)d_in[10], (const float*)d_in[16]};
    const float* rgcn_b[2]    = {(const float*)d_in[11], (const float*)d_in[17]};
    const float* mf_wl[2]     = {(const float*)d_in[12], (const float*)d_in[18]};
    const float* mf_bl[2]     = {(const float*)d_in[13], (const float*)d_in[19]};
    const float* mf_wr[2]     = {(const float*)d_in[14], (const float*)d_in[20]};

    char* p = (char*)d_ws;
    float* h32   = (float*)p; p += sizeof(float) * (size_t)Nn * Hd;
    __half* h16a = (__half*)p; p += sizeof(__half) * (size_t)Nn * Hd;
    __half* h16b = (__half*)p; p += sizeof(__half) * (size_t)Nn * Hd;
    float* gbuf  = (float*)p; p += sizeof(float) * (size_t)Ng * Hd;
    __half* wt16 = (__half*)p; p += sizeof(__half) * (size_t)2 * WT_PER_LAYER;
    __half* mfwt16 = (__half*)p; p += sizeof(__half) * (size_t)2 * MFWT_PER_LAYER;
    int* seg     = (int*)p;   p += sizeof(int) * (size_t)Ne;
    int* rank    = (int*)p;   p += sizeof(int) * (size_t)Ne;
    int* ssrc    = (int*)p;   p += sizeof(int) * (size_t)Ne;
    int* cnt     = (int*)p;   p += sizeof(int) * (size_t)NSEG;  // contiguous with bcnt/bfill
    int* bcnt    = (int*)p;   p += sizeof(int) * 16;
    int* bfill   = (int*)p;   p += sizeof(int) * 16;
    int* off     = (int*)p;   p += sizeof(int) * (size_t)(NSEG + 1);
    int* bsum    = (int*)p;   p += sizeof(int) * 1024;
    int* bbase   = (int*)p;   p += sizeof(int) * 16;
    int* order   = (int*)p;   p += sizeof(int) * (size_t)ORDER_SZ;

    hipMemsetAsync(cnt, 0, sizeof(int) * ((size_t)NSEG + 32), stream);
    hipMemsetAsync(gbuf, 0, sizeof(float) * (size_t)Ng * Hd, stream);

    k_prep<<<(PREP_TOTAL + 255) / 256, 256, 0, stream>>>(
        rgcn_w[0], rgcn_root[0], rgcn_w[1], rgcn_root[1],
        mf_wl[0], mf_wr[0], mf_wl[1], mf_wr[1], wt16, mfwt16);
    k_rel_emb<<<NB_RELSEG + NB_EMBED, 256, 0, stream>>>((const float4*)ea, eidx, seg, rank,
                                                        cnt, x, emb, h16a);
    k_scan1<<<SCAN_BLK, 256, 0, stream>>>(cnt, off, bsum, bcnt);
    k_scan2<<<1, 1024, 0, stream>>>(bsum, bcnt, bbase, order);
    k_scan3_bucket<<<SCAN_BLK, 256, 0, stream>>>(off, bsum, (const int4*)cnt, bbase,
                                                 bfill, order);
    k_scatter<<<Ne / 256, 256, 0, stream>>>(eidx, seg, rank, off, ssrc);

    __half* hin16 = h16a;  __half* hout16 = h16b;
    for (int b = 0; b < 2; b++) {
        k_rgcn_fused<<<NB_RG, 256, 0, stream>>>(hin16, off, ssrc, wt16 + b * WT_PER_LAYER,
                                                rgcn_b[b], hout16);
        k_mf_fused<<<NB_MF, 256, 0, stream>>>(hout16, off, ssrc, order,
                                              mfwt16 + b * MFWT_PER_LAYER, mf_bl[b],
                                              h32, hin16, b == 0 ? 1 : 0);
        // b=0: mf writes fp16 shadow into hin16 (next layer); b=1: fp32 into h32 (pool)
    }
    k_pool<<<Nn / 16, 256, 0, stream>>>(h32, batch, gbuf);
    k_head<<<Ng / 4, 256, 0, stream>>>(gbuf, lin1_w, lin1_b, lin2_w, lin2_b, (float*)d_out);
}